// Round 9
// baseline (189.353 us; speedup 1.0000x reference)
//
#include <hip/hip_runtime.h>

typedef __bf16 bf16;
typedef bf16 bf16x4 __attribute__((ext_vector_type(4)));
typedef bf16 bf16x8 __attribute__((ext_vector_type(8)));
typedef float floatx4 __attribute__((ext_vector_type(4)));

#define NB 8
#define NQ 1024
#define NK 1024
#define DIM 512
#define NH 8
#define DH 64

// async global->LDS, 16B per lane. LDS dest must be wave-uniform base + lane*16B.
__device__ __forceinline__ void async16(const void* g, void* l) {
    __builtin_amdgcn_global_load_lds(
        (const __attribute__((address_space(1))) unsigned int*)(unsigned long long)(g),
        (__attribute__((address_space(3))) unsigned int*)(unsigned long long)(l),
        16, 0, 0);
}

// ---------------------------------------------------------------------------
// prep_fused: blocks [0,4096): cast Q,K fp32->bf16 (float4 vectorized);
//             blocks [4096,4352): Wt[w][n][k] = (bf16)W[k][n], LDS 64x64 tiles.
// ---------------------------------------------------------------------------
__global__ __launch_bounds__(256) void prep_fused(
    const float* __restrict__ Q, const float* __restrict__ K,
    const float* __restrict__ Wq, const float* __restrict__ Wk,
    const float* __restrict__ Wv, const float* __restrict__ Wo,
    bf16* __restrict__ Qb, bf16* __restrict__ Kb, bf16* __restrict__ Wt)
{
    __shared__ bf16 Tl[64][68];
    const int bid = blockIdx.x;
    if (bid < 4096) {
        const int i = bid * 256 + threadIdx.x;   // float4 index
        float4 a = ((const float4*)Q)[i];
        float4 c = ((const float4*)K)[i];
        bf16x4 qa = {(bf16)a.x, (bf16)a.y, (bf16)a.z, (bf16)a.w};
        bf16x4 ka = {(bf16)c.x, (bf16)c.y, (bf16)c.z, (bf16)c.w};
        *(bf16x4*)(Qb + (size_t)i * 4) = qa;
        *(bf16x4*)(Kb + (size_t)i * 4) = ka;
    } else {
        const int bid2 = bid - 4096;
        const int w = bid2 >> 6;
        const int bx = bid2 & 7, by = (bid2 >> 3) & 7;
        const float* W = (w == 0) ? Wq : (w == 1) ? Wk : (w == 2) ? Wv : Wo;
        bf16* out = Wt + (size_t)w * DIM * DIM;
        const int k0 = bx * 64, n0 = by * 64;
        const int tx = threadIdx.x & 15, ty = threadIdx.x >> 4;
        for (int pass = 0; pass < 4; ++pass) {
            int k = ty + pass * 16;
            float4 v = *(const float4*)&W[(size_t)(k0 + k) * DIM + n0 + tx * 4];
            Tl[tx * 4 + 0][k] = (bf16)v.x;
            Tl[tx * 4 + 1][k] = (bf16)v.y;
            Tl[tx * 4 + 2][k] = (bf16)v.z;
            Tl[tx * 4 + 3][k] = (bf16)v.w;
        }
        __syncthreads();
        for (int pass = 0; pass < 4; ++pass) {
            int n = ty + pass * 16;
            bf16x4 ov = *(const bf16x4*)&Tl[n][tx * 4];
            *(bf16x4*)&out[(size_t)(n0 + n) * DIM + k0 + tx * 4] = ov;
        }
    }
}

// ---------------------------------------------------------------------------
// proj_fused: 128x64 tiles (M=128, N=64), BK=64, XOR-swizzled async staging,
// m-minor block mapping. LDS 48 KB -> 3 blocks/CU. Grid 1536 = 6/CU in two
// full rounds, 3 waves/SIMD. Wave grid 2x2, wave tile 64x32, acc[4][2].
// blocks [0,512):    Q proj -> Qp head layout [b,h,q,64], PRE-SCALED by
//                    SC = 1/(sqrt(64)*0.1)*log2(e) so attn S is exp2-ready.
// blocks [512,1536): KV proj: n<512 -> Kp head layout; n>=512 -> Vpt
//                    [b,h,d,1024] via in-LDS transpose (coalesced stores).
// ---------------------------------------------------------------------------
__global__ __launch_bounds__(256) void proj_fused(
    const bf16* __restrict__ Qb, const bf16* __restrict__ Kb,
    const bf16* __restrict__ Wt,
    const float* __restrict__ bq, const float* __restrict__ bk,
    const float* __restrict__ bv,
    bf16* __restrict__ Qp, bf16* __restrict__ Kp, bf16* __restrict__ Vpt)
{
    // 48 KB: A0(16K) | A1(16K) | B0(8K) | B1(8K)   (bf16 units: 8192|8192|4096|4096)
    __shared__ __attribute__((aligned(16))) bf16 sh[24576];
    const int t = threadIdx.x;
    const int wave = t >> 6, lane = t & 63, quad = lane >> 4, l16 = lane & 15;
    const int wr = wave >> 1, wc = wave & 1;
    const int bid = blockIdx.x;
    const bool isQ = bid < 512;
    const bf16* A; const bf16* W; int m0, n0;
    if (isQ) { A = Qb; W = Wt;             m0 = (bid & 63) * 128;  n0 = (bid >> 6) * 64; }
    else     { int b2 = bid - 512;
               A = Kb; W = Wt + 512 * DIM; m0 = (b2 & 63) * 128;   n0 = (b2 >> 6) * 64; }

    const int r1 = t >> 3, s1 = t & 7;
    const int p1 = s1 ^ (r1 & 7);          // rows r1+32j keep row&7
    const bf16* aSrc = A + (size_t)(m0 + r1) * DIM + p1 * 8;
    const bf16* wSrc = W + (size_t)(n0 + r1) * DIM + p1 * 8;

    floatx4 acc[4][2];
    for (int i = 0; i < 4; ++i)
        for (int j = 0; j < 2; ++j) acc[i][j] = (floatx4){0.f, 0.f, 0.f, 0.f};

    // prologue: issue kt=0 into buf 0
    #pragma unroll
    for (int j = 0; j < 4; ++j)
        async16(aSrc + (size_t)j * 32 * DIM, sh + (t + j * 256) * 8);
    #pragma unroll
    for (int j = 0; j < 2; ++j)
        async16(wSrc + (size_t)j * 32 * DIM, sh + 16384 + (t + j * 256) * 8);

    for (int kt = 0; kt < 8; ++kt) {
        __syncthreads();   // tile kt loads done; all waves done with other buf
        const int cur = kt & 1;
        bf16* Acur = sh + cur * 8192;
        bf16* Bcur = sh + 16384 + cur * 4096;
        if (kt < 7) {
            bf16* Anxt = sh + (1 - cur) * 8192;
            bf16* Bnxt = sh + 16384 + (1 - cur) * 4096;
            const int ko = (kt + 1) * 64;
            #pragma unroll
            for (int j = 0; j < 4; ++j)
                async16(aSrc + ko + (size_t)j * 32 * DIM, Anxt + (t + j * 256) * 8);
            #pragma unroll
            for (int j = 0; j < 2; ++j)
                async16(wSrc + ko + (size_t)j * 32 * DIM, Bnxt + (t + j * 256) * 8);
        }
        #pragma unroll
        for (int ks = 0; ks < 2; ++ks) {
            bf16x8 af[4], bfr[2];
            #pragma unroll
            for (int mi = 0; mi < 4; ++mi) {
                const int row = wr * 64 + mi * 16 + l16;
                af[mi] = *(const bf16x8*)(Acur + row * 64 + (((ks * 4 + quad) ^ (row & 7)) << 3));
            }
            #pragma unroll
            for (int ni = 0; ni < 2; ++ni) {
                const int row = wc * 32 + ni * 16 + l16;
                bfr[ni] = *(const bf16x8*)(Bcur + row * 64 + (((ks * 4 + quad) ^ (row & 7)) << 3));
            }
            #pragma unroll
            for (int mi = 0; mi < 4; ++mi)
                #pragma unroll
                for (int ni = 0; ni < 2; ++ni)
                    acc[mi][ni] = __builtin_amdgcn_mfma_f32_16x16x32_bf16(
                        af[mi], bfr[ni], acc[mi][ni], 0, 0, 0);
        }
    }

    const bool isV = (!isQ) && (n0 >= 512);
    if (!isV) {
        bf16* out = isQ ? Qp : Kp;
        const float* bias = isQ ? bq : bk;
        const float qscale = isQ ? 1.8033688f : 1.0f;   // SC folded into Qp
        for (int ni = 0; ni < 2; ++ni) {
            const int n = n0 + wc * 32 + ni * 16 + l16;
            const float bb = bias[n];
            const int hd = n >> 6, d = n & 63;
            for (int mi = 0; mi < 4; ++mi) {
                for (int r = 0; r < 4; ++r) {
                    const int m = m0 + wr * 64 + mi * 16 + quad * 4 + r;
                    const int b = m >> 10, q = m & 1023;
                    out[((size_t)(b * 8 + hd) * 1024 + q) * 64 + d] =
                        (bf16)((acc[mi][ni][r] + bb) * qscale);
                }
            }
        }
    } else {
        // dump tile (+bias) to LDS as Tb[n][m] (n local 0..63, 16 KB) with
        // chunk-XOR swizzle, then store coalesced rows of Vpt [b,h,d,1024]
        __syncthreads();
        for (int ni = 0; ni < 2; ++ni) {
            const int n = wc * 32 + ni * 16 + l16;           // local n 0..63
            const float bb = bv[n0 + n - 512];
            for (int mi = 0; mi < 4; ++mi) {
                const int mb = wr * 64 + mi * 16 + quad * 4;  // local m base (r=0..3)
                const int slot = ((mb >> 3) ^ (n & 15));
                bf16x4 pk = {(bf16)(acc[mi][ni][0] + bb), (bf16)(acc[mi][ni][1] + bb),
                             (bf16)(acc[mi][ni][2] + bb), (bf16)(acc[mi][ni][3] + bb)};
                *(bf16x4*)(sh + n * 128 + slot * 8 + (mb & 7)) = pk;
            }
        }
        __syncthreads();
        const int n = t >> 2, hf = t & 3;                     // 4 threads/row
        const int nv = n0 + n - 512, hd = nv >> 6, d = nv & 63;
        const int b = m0 >> 10, qb = m0 & 1023;
        bf16* dst = Vpt + ((size_t)(b * 8 + hd) * 64 + d) * 1024 + qb;
        #pragma unroll
        for (int j = 0; j < 4; ++j) {
            const int ch = hf * 4 + j;                        // 16 chunks of 8 m
            const int slot = ch ^ (n & 15);
            bf16x8 v8 = *(const bf16x8*)(sh + n * 128 + slot * 8);
            *(bf16x8*)(dst + ch * 8) = v8;
        }
    }
}

// ---------------------------------------------------------------------------
// attn: flash attention per (b,h). 1024 blocks x 4 waves, 64 q/block.
// 2x2 WAVE GRID: wave (wq,wk) owns 32 q x 32 keys of each 64x64 tile.
// Halves per-wave K/V LDS reads vs q-split (each wave reads only its key
// half: K 4 b128, V 4 b128, Pl 4 b64 w + 2 b128 r = ~12 equiv-b128/kt vs 22)
// while keeping ALL MFMAs at K=32 (8 QK + 8 PV + 2 osum, same as q-split —
// r7 showed K=16 MFMAs eat the LDS savings). Pl stays wave-private (no
// barrier). One-time 2-way cross-wave O/osum reduction through reused Kt
// LDS at the end, work split by qg (compile-time register indices only).
// Q pre-scaled in proj -> P = exp2(S). Mask: ballot fast path.
// ---------------------------------------------------------------------------
__global__ __launch_bounds__(256, 4) void attn_kernel(
    const bf16* __restrict__ Qp, const bf16* __restrict__ Kp,
    const bf16* __restrict__ Vpt, const int* __restrict__ mask,
    bf16* __restrict__ Oa)
{
    const int bh = blockIdx.x & 63, qblk = blockIdx.x >> 6;  // qblk 0..15
    const int b = bh >> 3, hd = bh & 7;
    const int t = threadIdx.x;
    const int wave = t >> 6, lane = t & 63, quad = lane >> 4, l16 = lane & 15;
    const int wq = wave >> 1, wk = wave & 1;

    __shared__ __attribute__((aligned(16))) bf16 Kt[2][64 * 64];
    __shared__ __attribute__((aligned(16))) bf16 Vt[2][64 * 64];
    __shared__ __attribute__((aligned(16))) bf16 Pl[4][32 * 32];  // per-wave P

    const bf16* Qbase = Qp + ((size_t)bh * NQ + qblk * 64 + wq * 32) * DH;
    const bf16* Kbase = Kp + (size_t)bh * NK * DH;
    const bf16* Vbase = Vpt + (size_t)bh * DH * NK;
    const int* mrow = mask + b * NK;

    // Q B-frags: qg in {0,1} covers q-local qg*16+l16; hh = d-half
    bf16x8 qf[2][2];
    #pragma unroll
    for (int qg = 0; qg < 2; ++qg)
        #pragma unroll
        for (int hh = 0; hh < 2; ++hh)
            qf[qg][hh] = *(const bf16x8*)(Qbase + (size_t)(qg * 16 + l16) * DH + hh * 32 + quad * 8);

    // all-ones B-frag for the denominator row-sum MFMA
    bf16x8 onesv;
    #pragma unroll
    for (int j = 0; j < 8; ++j) onesv[j] = (bf16)1.0f;

    // o[qg][dsub]: O-partial[q = wq*32+qg*16+quad*4+r][d = dsub*16+l16]
    floatx4 o[2][4];
    floatx4 osum[2];
    #pragma unroll
    for (int qg = 0; qg < 2; ++qg) {
        osum[qg] = (floatx4){0.f, 0.f, 0.f, 0.f};
        #pragma unroll
        for (int i = 0; i < 4; ++i) o[qg][i] = (floatx4){0.f, 0.f, 0.f, 0.f};
    }

    const int r1 = t >> 3, s1 = t & 7;
    const int p1 = s1 ^ (r1 & 7);          // (r1+32)&7 == r1&7
    const bf16* kSrc = Kbase + r1 * 64 + p1 * 8;            // + kt*4096
    const bf16* vSrc = Vbase + (size_t)r1 * 1024 + p1 * 8;  // + kt*64

    // prologue: issue tile 0 into buf 0
    async16(kSrc, Kt[0] + t * 8);
    async16(kSrc + 32 * 64, Kt[0] + (t + 256) * 8);
    async16(vSrc, Vt[0] + t * 8);
    async16(vSrc + (size_t)32 * 1024, Vt[0] + (t + 256) * 8);

    const int xor3 = (l16 & 3) ^ ((l16 >> 2) & 3);   // Pl slot swizzle

    for (int kt = 0; kt < NK / 64; ++kt) {
        __syncthreads();   // tile kt loads complete; all waves done with other buf
        const int cur = kt & 1;
        if (kt < NK / 64 - 1) {
            const int nxt = 1 - cur;
            async16(kSrc + (kt + 1) * 4096, Kt[nxt] + t * 8);
            async16(kSrc + (kt + 1) * 4096 + 32 * 64, Kt[nxt] + (t + 256) * 8);
            async16(vSrc + (kt + 1) * 64, Vt[nxt] + t * 8);
            async16(vSrc + (kt + 1) * 64 + (size_t)32 * 1024, Vt[nxt] + (t + 256) * 8);
        }

        // K A-frags: only this wave's 32-key half (2 subs x 2 d-halves)
        bf16x8 kb[2][2];
        #pragma unroll
        for (int sub = 0; sub < 2; ++sub) {
            const int rowk = wk * 32 + sub * 16 + l16;
            kb[sub][0] = *(const bf16x8*)(Kt[cur] + rowk * 64 + ((quad ^ (rowk & 7)) << 3));
            kb[sub][1] = *(const bf16x8*)(Kt[cur] + rowk * 64 + (((quad + 4) ^ (rowk & 7)) << 3));
        }
        // S^T = K Q^T: sf[sub][qg] = [key-in-sub quad*4+r][q = l16]
        floatx4 sf[2][2];
        __builtin_amdgcn_s_setprio(1);
        #pragma unroll
        for (int sub = 0; sub < 2; ++sub)
            #pragma unroll
            for (int qg = 0; qg < 2; ++qg) {
                floatx4 s = {0.f, 0.f, 0.f, 0.f};
                s = __builtin_amdgcn_mfma_f32_16x16x32_bf16(kb[sub][0], qf[qg][0], s, 0, 0, 0);
                s = __builtin_amdgcn_mfma_f32_16x16x32_bf16(kb[sub][1], qf[qg][1], s, 0, 0, 0);
                sf[sub][qg] = s;
            }
        __builtin_amdgcn_s_setprio(0);

        // mask: wave-uniform fast path (1 dword/lane + ballot per 64-key tile)
        const int mv = mrow[kt * 64 + lane];
        if (!__all(mv != 0)) {
            #pragma unroll
            for (int sub = 0; sub < 2; ++sub) {
                const int4 m4 = *(const int4*)&mrow[kt * 64 + wk * 32 + sub * 16 + quad * 4];
                #pragma unroll
                for (int qg = 0; qg < 2; ++qg) {
                    if (!m4.x) sf[sub][qg][0] = -3.0e38f;
                    if (!m4.y) sf[sub][qg][1] = -3.0e38f;
                    if (!m4.z) sf[sub][qg][2] = -3.0e38f;
                    if (!m4.w) sf[sub][qg][3] = -3.0e38f;
                }
            }
        }
        // P = exp2(S) (scale pre-folded into Qp); pack to wave-private Pl
        // Pl row = 32 keys (64B = 4 x 16B slots); slot = (sub*2+(quad>>1))^xor3
        #pragma unroll
        for (int sub = 0; sub < 2; ++sub)
            #pragma unroll
            for (int qg = 0; qg < 2; ++qg) {
                bf16x4 pk = {(bf16)__builtin_amdgcn_exp2f(sf[sub][qg][0]),
                             (bf16)__builtin_amdgcn_exp2f(sf[sub][qg][1]),
                             (bf16)__builtin_amdgcn_exp2f(sf[sub][qg][2]),
                             (bf16)__builtin_amdgcn_exp2f(sf[sub][qg][3])};
                const int slot = (sub * 2 + (quad >> 1)) ^ xor3;
                *(bf16x4*)&Pl[wave][(qg * 16 + l16) * 32 + slot * 8 + (quad & 1) * 4] = pk;
            }
        // P A-frags: row = q = l16, k = 8 keys at chunk quad (slot quad^xor3)
        bf16x8 af[2];
        #pragma unroll
        for (int qg = 0; qg < 2; ++qg)
            af[qg] = *(const bf16x8*)&Pl[wave][(qg * 16 + l16) * 32 + ((quad ^ xor3) << 3)];

        // PV + osum: one K=32 MFMA per (qg,dsub) over the wave's key half
        __builtin_amdgcn_s_setprio(1);
        osum[0] = __builtin_amdgcn_mfma_f32_16x16x32_bf16(af[0], onesv, osum[0], 0, 0, 0);
        osum[1] = __builtin_amdgcn_mfma_f32_16x16x32_bf16(af[1], onesv, osum[1], 0, 0, 0);
        #pragma unroll
        for (int dsub = 0; dsub < 4; ++dsub) {
            const int d = dsub * 16 + l16;
            bf16x8 vb = *(const bf16x8*)(Vt[cur] + d * 64 + (((wk * 4 + quad) ^ (d & 7)) << 3));
            o[0][dsub] = __builtin_amdgcn_mfma_f32_16x16x32_bf16(af[0], vb, o[0][dsub], 0, 0, 0);
            o[1][dsub] = __builtin_amdgcn_mfma_f32_16x16x32_bf16(af[1], vb, o[1][dsub], 0, 0, 0);
        }
        __builtin_amdgcn_s_setprio(0);
    }

    // ---- epilogue: 2-way cross-wave (wk) reduce, work split by qg ----
    __syncthreads();                       // all waves done with Kt/Vt
    float* scr  = (float*)Kt;              // 4 regions x 1024 fp32 (16 KB)
    float* scrL = (float*)Vt;              // 4 regions x 16 fp32

    {   // ship out the qg = 1-wk half (partner keeps/stores that q-range)
        float* reg = scr + wave * 1024;
        #pragma unroll
        for (int dsub = 0; dsub < 4; ++dsub)
            *(floatx4*)(reg + dsub * 256 + lane * 4) = o[1 - wk][dsub];
        if (l16 == 0) {
            #pragma unroll
            for (int r = 0; r < 4; ++r)
                scrL[wave * 16 + quad * 4 + r] = osum[1 - wk][r];
        }
    }
    __syncthreads();
    {   // receive partner's partial for own qg = wk; normalize; store
        const int partner = wq * 2 + (1 - wk);
        float* reg = scr + partner * 1024;
        #pragma unroll
        for (int dsub = 0; dsub < 4; ++dsub)
            o[wk][dsub] += *(const floatx4*)(reg + dsub * 256 + lane * 4);
        float linv[4];
        #pragma unroll
        for (int r = 0; r < 4; ++r)
            linv[r] = 1.f / (osum[wk][r] + scrL[partner * 16 + quad * 4 + r]);
        for (int dsub = 0; dsub < 4; ++dsub) {
            for (int r = 0; r < 4; ++r) {
                const int q = qblk * 64 + wq * 32 + wk * 16 + quad * 4 + r;
                const int col = hd * 64 + dsub * 16 + l16;
                Oa[((size_t)(b * NQ + q)) * DIM + col] = (bf16)(o[wk][dsub][r] * linv[r]);
            }
        }
    }
}

// ---------------------------------------------------------------------------
// ffn_gemm: 128x64 tiles (M=128, N=64), BK=64, XOR-swizzled staging,
// m-minor mapping, K-loop double-buffer. Grid 512, LDS 64 KB (A0|A1|B0|B1|R).
// Yb (bf16) = Oa + relu(Oa @ Wo^T + bo). Residual tile read from LDS stash.
// ---------------------------------------------------------------------------
__global__ __launch_bounds__(256) void ffn_gemm(
    const bf16* __restrict__ Oa, const bf16* __restrict__ W,
    const float* __restrict__ bias, bf16* __restrict__ Yb)
{
    __shared__ __attribute__((aligned(16))) bf16 sh[32768];  // 64 KB
    const int t = threadIdx.x;
    const int wave = t >> 6, lane = t & 63, quad = lane >> 4, l16 = lane & 15;
    const int wr = wave >> 1, wc = wave & 1;
    const int m0 = (blockIdx.x & 63) * 128, n0 = (blockIdx.x >> 6) * 64;
    const int ktr = n0 >> 6;               // K-iter whose A-tile == residual tile

    const int r1 = t >> 3, s1 = t & 7;
    const int p1 = s1 ^ (r1 & 7);
    const bf16* aSrc = Oa + (size_t)(m0 + r1) * DIM + p1 * 8;
    const bf16* wSrc = W  + (size_t)(n0 + r1) * DIM + p1 * 8;

    floatx4 acc[4][2];
    for (int i = 0; i < 4; ++i)
        for (int j = 0; j < 2; ++j) acc[i][j] = (floatx4){0.f, 0.f, 0.f, 0.f};

    #pragma unroll
    for (int j = 0; j < 4; ++j)
        async16(aSrc + (size_t)j * 32 * DIM, sh + (t + j * 256) * 8);
    #pragma unroll
    for (int j = 0; j < 2; ++j)
        async16(wSrc + (size_t)j * 32 * DIM, sh + 16384 + (t + j * 256) * 8);

    for (int kt = 0; kt < 8; ++kt) {
        __syncthreads();
        const int cur = kt & 1;
        bf16* Acur = sh + cur * 8192;
        bf16* Bcur = sh + 16384 + cur * 4096;
        if (kt < 7) {
            bf16* Anxt = sh + (1 - cur) * 8192;
            bf16* Bnxt = sh + 16384 + (1 - cur) * 4096;
            const int ko = (kt + 1) * 64;
            #pragma unroll
            for (int j = 0; j < 4; ++j)
                async16(aSrc + ko + (size_t)j * 32 * DIM, Anxt + (t + j * 256) * 8);
            #pragma unroll
            for (int j = 0; j < 2; ++j)
                async16(wSrc + ko + (size_t)j * 32 * DIM, Bnxt + (t + j * 256) * 8);
        }
        if (kt == ktr) {   // stash residual tile (uniform branch, once/block)
            #pragma unroll
            for (int j = 0; j < 4; ++j) {
                const int idx = t + j * 256;
                *(bf16x8*)(sh + 24576 + idx * 8) = *(const bf16x8*)(Acur + idx * 8);
            }
        }
        #pragma unroll
        for (int ks = 0; ks < 2; ++ks) {
            bf16x8 af[4], bfr[2];
            #pragma unroll
            for (int mi = 0; mi < 4; ++mi) {
                const int row = wr * 64 + mi * 16 + l16;
                af[mi] = *(const bf16x8*)(Acur + row * 64 + (((ks * 4 + quad) ^ (row & 7)) << 3));
            }
            #pragma unroll
            for (int ni = 0; ni < 2; ++ni) {
                const int row = wc * 32 + ni * 16 + l16;
                bfr[ni] = *(const bf16x8*)(Bcur + row * 64 + (((ks * 4 + quad) ^ (row & 7)) << 3));
            }
            #pragma unroll
            for (int mi = 0; mi < 4; ++mi)
                #pragma unroll
                for (int ni = 0; ni < 2; ++ni)
                    acc[mi][ni] = __builtin_amdgcn_mfma_f32_16x16x32_bf16(
                        af[mi], bfr[ni], acc[mi][ni], 0, 0, 0);
        }
    }
    __syncthreads();       // R complete (covers ktr == 7)

    for (int ni = 0; ni < 2; ++ni) {
        const int n = n0 + wc * 32 + ni * 16 + l16;
        const int cl = wc * 32 + ni * 16 + l16;          // local col in R
        const int chi = cl >> 3, clo = cl & 7;
        const float bb = bias[n];
        for (int mi = 0; mi < 4; ++mi) {
            for (int r = 0; r < 4; ++r) {
                const int rl = wr * 64 + mi * 16 + quad * 4 + r;   // local row
                const float ov = (float)sh[24576 + rl * 64 + ((chi ^ (rl & 7)) << 3) + clo];
                Yb[(size_t)(m0 + rl) * DIM + n] = (bf16)(ov + fmaxf(acc[mi][ni][r] + bb, 0.f));
            }
        }
    }
}

// ---------------------------------------------------------------------------
// ln: LayerNorm over last dim (512). One wave per row; bf16 in, fp32 out.
// ---------------------------------------------------------------------------
__global__ __launch_bounds__(256) void ln_kernel(
    const bf16* __restrict__ Y, const float* __restrict__ gamma,
    const float* __restrict__ beta, float* __restrict__ out)
{
    const int row  = blockIdx.x * 4 + (threadIdx.x >> 6);
    const int lane = threadIdx.x & 63;
    bf16x8 v = *(const bf16x8*)(Y + (size_t)row * DIM + lane * 8);
    float f[8];
    float s = 0.f, sq = 0.f;
    #pragma unroll
    for (int j = 0; j < 8; ++j) {
        f[j] = (float)v[j];
        s += f[j];
        sq += f[j] * f[j];
    }
    for (int mk = 32; mk >= 1; mk >>= 1) {
        s  += __shfl_xor(s,  mk, 64);
        sq += __shfl_xor(sq, mk, 64);
    }
    const float mu  = s * (1.f / 512.f);
    const float var = sq * (1.f / 512.f) - mu * mu;
    const float inv = rsqrtf(var + 1e-5f);
    float4 g1 = ((const float4*)gamma)[lane * 2];
    float4 g2 = ((const float4*)gamma)[lane * 2 + 1];
    float4 b1 = ((const float4*)beta)[lane * 2];
    float4 b2 = ((const float4*)beta)[lane * 2 + 1];
    float4 o1, o2;
    o1.x = (f[0] - mu) * inv * g1.x + b1.x;
    o1.y = (f[1] - mu) * inv * g1.y + b1.y;
    o1.z = (f[2] - mu) * inv * g1.z + b1.z;
    o1.w = (f[3] - mu) * inv * g1.w + b1.w;
    o2.x = (f[4] - mu) * inv * g2.x + b2.x;
    o2.y = (f[5] - mu) * inv * g2.y + b2.y;
    o2.z = (f[6] - mu) * inv * g2.z + b2.z;
    o2.w = (f[7] - mu) * inv * g2.w + b2.w;
    float* orow = out + (size_t)row * DIM;
    ((float4*)orow)[lane * 2]     = o1;
    ((float4*)orow)[lane * 2 + 1] = o2;
}

// ---------------------------------------------------------------------------
extern "C" void kernel_launch(void* const* d_in, const int* in_sizes, int n_in,
                              void* d_out, int out_size, void* d_ws, size_t ws_size,
                              hipStream_t stream) {
    const float* Q  = (const float*)d_in[0];
    const float* K  = (const float*)d_in[1];
    const int*   mask = (const int*)d_in[2];
    const float* Wq = (const float*)d_in[3];
    const float* bq = (const float*)d_in[4];
    const float* Wk = (const float*)d_in[5];
    const float* bk = (const float*)d_in[6];
    const float* Wv = (const float*)d_in[7];
    const float* bv = (const float*)d_in[8];
    const float* Wo = (const float*)d_in[9];
    const float* bo = (const float*)d_in[10];
    const float* gamma = (const float*)d_in[11];
    const float* beta  = (const float*)d_in[12];

    char* ws = (char*)d_ws;
    bf16* Wt  = (bf16*)(ws);                   // 2 MB (4 x 512x512 bf16, transposed)
    bf16* Qb  = (bf16*)(ws + 2097152);         // 8 MB
    bf16* Kb  = (bf16*)(ws + 10485760);        // 8 MB
    bf16* Qp  = (bf16*)(ws + 18874368);        // 8 MB  [b,h,q,64] (pre-scaled)
    bf16* Kp  = (bf16*)(ws + 27262976);        // 8 MB  [b,h,k,64]
    bf16* Vpt = (bf16*)(ws + 35651584);        // 8 MB  [b,h,d,1024]
    bf16* Oa  = (bf16*)(ws + 44040192);        // 8 MB  [b,q,512]
    bf16* Yb  = (bf16*)(ws + 52428800);        // 8 MB  [b,q,512] bf16
    float* out = (float*)d_out;

    prep_fused<<<4352, 256, 0, stream>>>(Q, K, Wq, Wk, Wv, Wo, Qb, Kb, Wt);
    proj_fused<<<1536, 256, 0, stream>>>(Qb, Kb, Wt, bq, bk, bv, Qp, Kp, Vpt);
    attn_kernel<<<1024, 256, 0, stream>>>(Qp, Kp, Vpt, mask, Oa);
    ffn_gemm<<<512, 256, 0, stream>>>(Oa, Wt + 3 * 262144, bo, Yb);
    ln_kernel<<<2048, 256, 0, stream>>>(Yb, gamma, beta, out);
}

// Round 10
// 161.511 us; speedup vs baseline: 1.1724x; 1.1724x over previous
//
#include <hip/hip_runtime.h>

typedef __bf16 bf16;
typedef bf16 bf16x4 __attribute__((ext_vector_type(4)));
typedef bf16 bf16x8 __attribute__((ext_vector_type(8)));
typedef float floatx4 __attribute__((ext_vector_type(4)));

#define NB 8
#define NQ 1024
#define NK 1024
#define DIM 512
#define NH 8
#define DH 64

// async global->LDS, 16B per lane. LDS dest must be wave-uniform base + lane*16B.
__device__ __forceinline__ void async16(const void* g, void* l) {
    __builtin_amdgcn_global_load_lds(
        (const __attribute__((address_space(1))) unsigned int*)(unsigned long long)(g),
        (__attribute__((address_space(3))) unsigned int*)(unsigned long long)(l),
        16, 0, 0);
}

// ---------------------------------------------------------------------------
// prep_fused: blocks [0,4096): cast Q,K fp32->bf16 (float4 vectorized);
//             blocks [4096,4352): Wt[w][n][k] = (bf16)W[k][n], LDS 64x64 tiles.
// ---------------------------------------------------------------------------
__global__ __launch_bounds__(256) void prep_fused(
    const float* __restrict__ Q, const float* __restrict__ K,
    const float* __restrict__ Wq, const float* __restrict__ Wk,
    const float* __restrict__ Wv, const float* __restrict__ Wo,
    bf16* __restrict__ Qb, bf16* __restrict__ Kb, bf16* __restrict__ Wt)
{
    __shared__ bf16 Tl[64][68];
    const int bid = blockIdx.x;
    if (bid < 4096) {
        const int i = bid * 256 + threadIdx.x;   // float4 index
        float4 a = ((const float4*)Q)[i];
        float4 c = ((const float4*)K)[i];
        bf16x4 qa = {(bf16)a.x, (bf16)a.y, (bf16)a.z, (bf16)a.w};
        bf16x4 ka = {(bf16)c.x, (bf16)c.y, (bf16)c.z, (bf16)c.w};
        *(bf16x4*)(Qb + (size_t)i * 4) = qa;
        *(bf16x4*)(Kb + (size_t)i * 4) = ka;
    } else {
        const int bid2 = bid - 4096;
        const int w = bid2 >> 6;
        const int bx = bid2 & 7, by = (bid2 >> 3) & 7;
        const float* W = (w == 0) ? Wq : (w == 1) ? Wk : (w == 2) ? Wv : Wo;
        bf16* out = Wt + (size_t)w * DIM * DIM;
        const int k0 = bx * 64, n0 = by * 64;
        const int tx = threadIdx.x & 15, ty = threadIdx.x >> 4;
        for (int pass = 0; pass < 4; ++pass) {
            int k = ty + pass * 16;
            float4 v = *(const float4*)&W[(size_t)(k0 + k) * DIM + n0 + tx * 4];
            Tl[tx * 4 + 0][k] = (bf16)v.x;
            Tl[tx * 4 + 1][k] = (bf16)v.y;
            Tl[tx * 4 + 2][k] = (bf16)v.z;
            Tl[tx * 4 + 3][k] = (bf16)v.w;
        }
        __syncthreads();
        for (int pass = 0; pass < 4; ++pass) {
            int n = ty + pass * 16;
            bf16x4 ov = *(const bf16x4*)&Tl[n][tx * 4];
            *(bf16x4*)&out[(size_t)(n0 + n) * DIM + k0 + tx * 4] = ov;
        }
    }
}

// ---------------------------------------------------------------------------
// proj_fused: 128x64 tiles (M=128, N=64), BK=64, XOR-swizzled async staging,
// m-minor block mapping. LDS 48 KB -> 3 blocks/CU. Grid 1536 = 6/CU in two
// full rounds, 3 waves/SIMD. Wave grid 2x2, wave tile 64x32, acc[4][2].
// blocks [0,512):    Q proj -> Qp head layout [b,h,q,64], PRE-SCALED by
//                    SC = 1/(sqrt(64)*0.1)*log2(e) so attn S is exp2-ready.
// blocks [512,1536): KV proj: n<512 -> Kp head layout; n>=512 -> Vpt
//                    [b,h,d,1024] via in-LDS transpose (coalesced stores).
// ---------------------------------------------------------------------------
__global__ __launch_bounds__(256) void proj_fused(
    const bf16* __restrict__ Qb, const bf16* __restrict__ Kb,
    const bf16* __restrict__ Wt,
    const float* __restrict__ bq, const float* __restrict__ bk,
    const float* __restrict__ bv,
    bf16* __restrict__ Qp, bf16* __restrict__ Kp, bf16* __restrict__ Vpt)
{
    // 48 KB: A0(16K) | A1(16K) | B0(8K) | B1(8K)   (bf16 units: 8192|8192|4096|4096)
    __shared__ __attribute__((aligned(16))) bf16 sh[24576];
    const int t = threadIdx.x;
    const int wave = t >> 6, lane = t & 63, quad = lane >> 4, l16 = lane & 15;
    const int wr = wave >> 1, wc = wave & 1;
    const int bid = blockIdx.x;
    const bool isQ = bid < 512;
    const bf16* A; const bf16* W; int m0, n0;
    if (isQ) { A = Qb; W = Wt;             m0 = (bid & 63) * 128;  n0 = (bid >> 6) * 64; }
    else     { int b2 = bid - 512;
               A = Kb; W = Wt + 512 * DIM; m0 = (b2 & 63) * 128;   n0 = (b2 >> 6) * 64; }

    const int r1 = t >> 3, s1 = t & 7;
    const int p1 = s1 ^ (r1 & 7);          // rows r1+32j keep row&7
    const bf16* aSrc = A + (size_t)(m0 + r1) * DIM + p1 * 8;
    const bf16* wSrc = W + (size_t)(n0 + r1) * DIM + p1 * 8;

    floatx4 acc[4][2];
    for (int i = 0; i < 4; ++i)
        for (int j = 0; j < 2; ++j) acc[i][j] = (floatx4){0.f, 0.f, 0.f, 0.f};

    // prologue: issue kt=0 into buf 0
    #pragma unroll
    for (int j = 0; j < 4; ++j)
        async16(aSrc + (size_t)j * 32 * DIM, sh + (t + j * 256) * 8);
    #pragma unroll
    for (int j = 0; j < 2; ++j)
        async16(wSrc + (size_t)j * 32 * DIM, sh + 16384 + (t + j * 256) * 8);

    for (int kt = 0; kt < 8; ++kt) {
        __syncthreads();   // tile kt loads done; all waves done with other buf
        const int cur = kt & 1;
        bf16* Acur = sh + cur * 8192;
        bf16* Bcur = sh + 16384 + cur * 4096;
        if (kt < 7) {
            bf16* Anxt = sh + (1 - cur) * 8192;
            bf16* Bnxt = sh + 16384 + (1 - cur) * 4096;
            const int ko = (kt + 1) * 64;
            #pragma unroll
            for (int j = 0; j < 4; ++j)
                async16(aSrc + ko + (size_t)j * 32 * DIM, Anxt + (t + j * 256) * 8);
            #pragma unroll
            for (int j = 0; j < 2; ++j)
                async16(wSrc + ko + (size_t)j * 32 * DIM, Bnxt + (t + j * 256) * 8);
        }
        #pragma unroll
        for (int ks = 0; ks < 2; ++ks) {
            bf16x8 af[4], bfr[2];
            #pragma unroll
            for (int mi = 0; mi < 4; ++mi) {
                const int row = wr * 64 + mi * 16 + l16;
                af[mi] = *(const bf16x8*)(Acur + row * 64 + (((ks * 4 + quad) ^ (row & 7)) << 3));
            }
            #pragma unroll
            for (int ni = 0; ni < 2; ++ni) {
                const int row = wc * 32 + ni * 16 + l16;
                bfr[ni] = *(const bf16x8*)(Bcur + row * 64 + (((ks * 4 + quad) ^ (row & 7)) << 3));
            }
            #pragma unroll
            for (int mi = 0; mi < 4; ++mi)
                #pragma unroll
                for (int ni = 0; ni < 2; ++ni)
                    acc[mi][ni] = __builtin_amdgcn_mfma_f32_16x16x32_bf16(
                        af[mi], bfr[ni], acc[mi][ni], 0, 0, 0);
        }
    }

    const bool isV = (!isQ) && (n0 >= 512);
    if (!isV) {
        bf16* out = isQ ? Qp : Kp;
        const float* bias = isQ ? bq : bk;
        const float qscale = isQ ? 1.8033688f : 1.0f;   // SC folded into Qp
        for (int ni = 0; ni < 2; ++ni) {
            const int n = n0 + wc * 32 + ni * 16 + l16;
            const float bb = bias[n];
            const int hd = n >> 6, d = n & 63;
            for (int mi = 0; mi < 4; ++mi) {
                for (int r = 0; r < 4; ++r) {
                    const int m = m0 + wr * 64 + mi * 16 + quad * 4 + r;
                    const int b = m >> 10, q = m & 1023;
                    out[((size_t)(b * 8 + hd) * 1024 + q) * 64 + d] =
                        (bf16)((acc[mi][ni][r] + bb) * qscale);
                }
            }
        }
    } else {
        // dump tile (+bias) to LDS as Tb[n][m] (n local 0..63, 16 KB) with
        // chunk-XOR swizzle, then store coalesced rows of Vpt [b,h,d,1024]
        __syncthreads();
        for (int ni = 0; ni < 2; ++ni) {
            const int n = wc * 32 + ni * 16 + l16;           // local n 0..63
            const float bb = bv[n0 + n - 512];
            for (int mi = 0; mi < 4; ++mi) {
                const int mb = wr * 64 + mi * 16 + quad * 4;  // local m base (r=0..3)
                const int slot = ((mb >> 3) ^ (n & 15));
                bf16x4 pk = {(bf16)(acc[mi][ni][0] + bb), (bf16)(acc[mi][ni][1] + bb),
                             (bf16)(acc[mi][ni][2] + bb), (bf16)(acc[mi][ni][3] + bb)};
                *(bf16x4*)(sh + n * 128 + slot * 8 + (mb & 7)) = pk;
            }
        }
        __syncthreads();
        const int n = t >> 2, hf = t & 3;                     // 4 threads/row
        const int nv = n0 + n - 512, hd = nv >> 6, d = nv & 63;
        const int b = m0 >> 10, qb = m0 & 1023;
        bf16* dst = Vpt + ((size_t)(b * 8 + hd) * 64 + d) * 1024 + qb;
        #pragma unroll
        for (int j = 0; j < 4; ++j) {
            const int ch = hf * 4 + j;                        // 16 chunks of 8 m
            const int slot = ch ^ (n & 15);
            bf16x8 v8 = *(const bf16x8*)(sh + n * 128 + slot * 8);
            *(bf16x8*)(dst + ch * 8) = v8;
        }
    }
}

// ---------------------------------------------------------------------------
// attn: flash attention per (b,h). 1024 blocks x 4 waves, 64 q/block.
// 2x2 WAVE GRID: wave (wq,wk) owns 32 q x 32 keys of each 64x64 tile.
// Halves per-wave K/V LDS reads vs q-split while keeping ALL MFMAs at K=32
// (18/wave/kt, same as q-split). Pl wave-private (no barrier).
// EPILOGUE FIX vs r9 (rule #20): o[1-wk]/osum[1-wk] were RUNTIME register
// indices -> whole acc array demoted to scratch (VGPR 60, WRITE 28MB, 84us).
// Now a wave-uniform if(wk==0)/else with LITERAL indices on both sides.
// Q pre-scaled in proj -> P = exp2(S). Mask: ballot fast path.
// ---------------------------------------------------------------------------
__global__ __launch_bounds__(256, 4) void attn_kernel(
    const bf16* __restrict__ Qp, const bf16* __restrict__ Kp,
    const bf16* __restrict__ Vpt, const int* __restrict__ mask,
    bf16* __restrict__ Oa)
{
    const int bh = blockIdx.x & 63, qblk = blockIdx.x >> 6;  // qblk 0..15
    const int b = bh >> 3, hd = bh & 7;
    const int t = threadIdx.x;
    const int wave = t >> 6, lane = t & 63, quad = lane >> 4, l16 = lane & 15;
    const int wq = wave >> 1, wk = wave & 1;

    __shared__ __attribute__((aligned(16))) bf16 Kt[2][64 * 64];
    __shared__ __attribute__((aligned(16))) bf16 Vt[2][64 * 64];
    __shared__ __attribute__((aligned(16))) bf16 Pl[4][32 * 32];  // per-wave P

    const bf16* Qbase = Qp + ((size_t)bh * NQ + qblk * 64 + wq * 32) * DH;
    const bf16* Kbase = Kp + (size_t)bh * NK * DH;
    const bf16* Vbase = Vpt + (size_t)bh * DH * NK;
    const int* mrow = mask + b * NK;

    // Q B-frags: qg in {0,1} covers q-local qg*16+l16; hh = d-half
    bf16x8 qf[2][2];
    #pragma unroll
    for (int qg = 0; qg < 2; ++qg)
        #pragma unroll
        for (int hh = 0; hh < 2; ++hh)
            qf[qg][hh] = *(const bf16x8*)(Qbase + (size_t)(qg * 16 + l16) * DH + hh * 32 + quad * 8);

    // all-ones B-frag for the denominator row-sum MFMA
    bf16x8 onesv;
    #pragma unroll
    for (int j = 0; j < 8; ++j) onesv[j] = (bf16)1.0f;

    // o[qg][dsub]: O-partial[q = wq*32+qg*16+quad*4+r][d = dsub*16+l16]
    floatx4 o[2][4];
    floatx4 osum[2];
    #pragma unroll
    for (int qg = 0; qg < 2; ++qg) {
        osum[qg] = (floatx4){0.f, 0.f, 0.f, 0.f};
        #pragma unroll
        for (int i = 0; i < 4; ++i) o[qg][i] = (floatx4){0.f, 0.f, 0.f, 0.f};
    }

    const int r1 = t >> 3, s1 = t & 7;
    const int p1 = s1 ^ (r1 & 7);          // (r1+32)&7 == r1&7
    const bf16* kSrc = Kbase + r1 * 64 + p1 * 8;            // + kt*4096
    const bf16* vSrc = Vbase + (size_t)r1 * 1024 + p1 * 8;  // + kt*64

    // prologue: issue tile 0 into buf 0
    async16(kSrc, Kt[0] + t * 8);
    async16(kSrc + 32 * 64, Kt[0] + (t + 256) * 8);
    async16(vSrc, Vt[0] + t * 8);
    async16(vSrc + (size_t)32 * 1024, Vt[0] + (t + 256) * 8);

    const int xor3 = (l16 & 3) ^ ((l16 >> 2) & 3);   // Pl slot swizzle

    for (int kt = 0; kt < NK / 64; ++kt) {
        __syncthreads();   // tile kt loads complete; all waves done with other buf
        const int cur = kt & 1;
        if (kt < NK / 64 - 1) {
            const int nxt = 1 - cur;
            async16(kSrc + (kt + 1) * 4096, Kt[nxt] + t * 8);
            async16(kSrc + (kt + 1) * 4096 + 32 * 64, Kt[nxt] + (t + 256) * 8);
            async16(vSrc + (kt + 1) * 64, Vt[nxt] + t * 8);
            async16(vSrc + (kt + 1) * 64 + (size_t)32 * 1024, Vt[nxt] + (t + 256) * 8);
        }

        // K A-frags: only this wave's 32-key half (2 subs x 2 d-halves)
        bf16x8 kb[2][2];
        #pragma unroll
        for (int sub = 0; sub < 2; ++sub) {
            const int rowk = wk * 32 + sub * 16 + l16;
            kb[sub][0] = *(const bf16x8*)(Kt[cur] + rowk * 64 + ((quad ^ (rowk & 7)) << 3));
            kb[sub][1] = *(const bf16x8*)(Kt[cur] + rowk * 64 + (((quad + 4) ^ (rowk & 7)) << 3));
        }
        // S^T = K Q^T: sf[sub][qg] = [key-in-sub quad*4+r][q = l16]
        floatx4 sf[2][2];
        __builtin_amdgcn_s_setprio(1);
        #pragma unroll
        for (int sub = 0; sub < 2; ++sub)
            #pragma unroll
            for (int qg = 0; qg < 2; ++qg) {
                floatx4 s = {0.f, 0.f, 0.f, 0.f};
                s = __builtin_amdgcn_mfma_f32_16x16x32_bf16(kb[sub][0], qf[qg][0], s, 0, 0, 0);
                s = __builtin_amdgcn_mfma_f32_16x16x32_bf16(kb[sub][1], qf[qg][1], s, 0, 0, 0);
                sf[sub][qg] = s;
            }
        __builtin_amdgcn_s_setprio(0);

        // mask: wave-uniform fast path (1 dword/lane + ballot per 64-key tile)
        const int mv = mrow[kt * 64 + lane];
        if (!__all(mv != 0)) {
            #pragma unroll
            for (int sub = 0; sub < 2; ++sub) {
                const int4 m4 = *(const int4*)&mrow[kt * 64 + wk * 32 + sub * 16 + quad * 4];
                #pragma unroll
                for (int qg = 0; qg < 2; ++qg) {
                    if (!m4.x) sf[sub][qg][0] = -3.0e38f;
                    if (!m4.y) sf[sub][qg][1] = -3.0e38f;
                    if (!m4.z) sf[sub][qg][2] = -3.0e38f;
                    if (!m4.w) sf[sub][qg][3] = -3.0e38f;
                }
            }
        }
        // P = exp2(S) (scale pre-folded into Qp); pack to wave-private Pl
        // Pl row = 32 keys (64B = 4 x 16B slots); slot = (sub*2+(quad>>1))^xor3
        #pragma unroll
        for (int sub = 0; sub < 2; ++sub)
            #pragma unroll
            for (int qg = 0; qg < 2; ++qg) {
                bf16x4 pk = {(bf16)__builtin_amdgcn_exp2f(sf[sub][qg][0]),
                             (bf16)__builtin_amdgcn_exp2f(sf[sub][qg][1]),
                             (bf16)__builtin_amdgcn_exp2f(sf[sub][qg][2]),
                             (bf16)__builtin_amdgcn_exp2f(sf[sub][qg][3])};
                const int slot = (sub * 2 + (quad >> 1)) ^ xor3;
                *(bf16x4*)&Pl[wave][(qg * 16 + l16) * 32 + slot * 8 + (quad & 1) * 4] = pk;
            }
        // P A-frags: row = q = l16, k = 8 keys at chunk quad (slot quad^xor3)
        bf16x8 af[2];
        #pragma unroll
        for (int qg = 0; qg < 2; ++qg)
            af[qg] = *(const bf16x8*)&Pl[wave][(qg * 16 + l16) * 32 + ((quad ^ xor3) << 3)];

        // PV + osum: one K=32 MFMA per (qg,dsub) over the wave's key half
        __builtin_amdgcn_s_setprio(1);
        osum[0] = __builtin_amdgcn_mfma_f32_16x16x32_bf16(af[0], onesv, osum[0], 0, 0, 0);
        osum[1] = __builtin_amdgcn_mfma_f32_16x16x32_bf16(af[1], onesv, osum[1], 0, 0, 0);
        #pragma unroll
        for (int dsub = 0; dsub < 4; ++dsub) {
            const int d = dsub * 16 + l16;
            bf16x8 vb = *(const bf16x8*)(Vt[cur] + d * 64 + (((wk * 4 + quad) ^ (d & 7)) << 3));
            o[0][dsub] = __builtin_amdgcn_mfma_f32_16x16x32_bf16(af[0], vb, o[0][dsub], 0, 0, 0);
            o[1][dsub] = __builtin_amdgcn_mfma_f32_16x16x32_bf16(af[1], vb, o[1][dsub], 0, 0, 0);
        }
        __builtin_amdgcn_s_setprio(0);
    }

    // ---- epilogue: 2-way cross-wave (wk) reduce, LITERAL reg indices only ----
    __syncthreads();                       // all waves done with Kt/Vt
    float* scr  = (float*)Kt;              // 4 regions x 1024 fp32 (16 KB)
    float* scrL = (float*)Vt;              // 4 regions x 16 fp32

    // ship out the q-half this wave does NOT store (qg = 1-wk), via uniform branch
    {
        float* reg = scr + wave * 1024;
        if (wk == 0) {
            #pragma unroll
            for (int dsub = 0; dsub < 4; ++dsub)
                *(floatx4*)(reg + dsub * 256 + lane * 4) = o[1][dsub];
            if (l16 == 0) {
                #pragma unroll
                for (int r = 0; r < 4; ++r)
                    scrL[wave * 16 + quad * 4 + r] = osum[1][r];
            }
        } else {
            #pragma unroll
            for (int dsub = 0; dsub < 4; ++dsub)
                *(floatx4*)(reg + dsub * 256 + lane * 4) = o[0][dsub];
            if (l16 == 0) {
                #pragma unroll
                for (int r = 0; r < 4; ++r)
                    scrL[wave * 16 + quad * 4 + r] = osum[0][r];
            }
        }
    }
    __syncthreads();
    {   // keep own half (qg = wk) in named regs via uniform branch; reduce; store
        const int partner = wq * 2 + (1 - wk);
        float* reg = scr + partner * 1024;
        floatx4 oo[4];
        floatx4 os;
        if (wk == 0) {
            oo[0] = o[0][0]; oo[1] = o[0][1]; oo[2] = o[0][2]; oo[3] = o[0][3];
            os = osum[0];
        } else {
            oo[0] = o[1][0]; oo[1] = o[1][1]; oo[2] = o[1][2]; oo[3] = o[1][3];
            os = osum[1];
        }
        #pragma unroll
        for (int dsub = 0; dsub < 4; ++dsub)
            oo[dsub] += *(const floatx4*)(reg + dsub * 256 + lane * 4);
        float linv[4];
        #pragma unroll
        for (int r = 0; r < 4; ++r)
            linv[r] = 1.f / (os[r] + scrL[partner * 16 + quad * 4 + r]);
        for (int dsub = 0; dsub < 4; ++dsub) {
            for (int r = 0; r < 4; ++r) {
                const int q = qblk * 64 + wq * 32 + wk * 16 + quad * 4 + r;
                const int col = hd * 64 + dsub * 16 + l16;
                Oa[((size_t)(b * NQ + q)) * DIM + col] = (bf16)(oo[dsub][r] * linv[r]);
            }
        }
    }
}

// ---------------------------------------------------------------------------
// ffn_gemm: 128x64 tiles (M=128, N=64), BK=64, XOR-swizzled staging,
// m-minor mapping, K-loop double-buffer. Grid 512, LDS 64 KB (A0|A1|B0|B1|R).
// Yb (bf16) = Oa + relu(Oa @ Wo^T + bo). Residual tile read from LDS stash.
// ---------------------------------------------------------------------------
__global__ __launch_bounds__(256) void ffn_gemm(
    const bf16* __restrict__ Oa, const bf16* __restrict__ W,
    const float* __restrict__ bias, bf16* __restrict__ Yb)
{
    __shared__ __attribute__((aligned(16))) bf16 sh[32768];  // 64 KB
    const int t = threadIdx.x;
    const int wave = t >> 6, lane = t & 63, quad = lane >> 4, l16 = lane & 15;
    const int wr = wave >> 1, wc = wave & 1;
    const int m0 = (blockIdx.x & 63) * 128, n0 = (blockIdx.x >> 6) * 64;
    const int ktr = n0 >> 6;               // K-iter whose A-tile == residual tile

    const int r1 = t >> 3, s1 = t & 7;
    const int p1 = s1 ^ (r1 & 7);
    const bf16* aSrc = Oa + (size_t)(m0 + r1) * DIM + p1 * 8;
    const bf16* wSrc = W  + (size_t)(n0 + r1) * DIM + p1 * 8;

    floatx4 acc[4][2];
    for (int i = 0; i < 4; ++i)
        for (int j = 0; j < 2; ++j) acc[i][j] = (floatx4){0.f, 0.f, 0.f, 0.f};

    #pragma unroll
    for (int j = 0; j < 4; ++j)
        async16(aSrc + (size_t)j * 32 * DIM, sh + (t + j * 256) * 8);
    #pragma unroll
    for (int j = 0; j < 2; ++j)
        async16(wSrc + (size_t)j * 32 * DIM, sh + 16384 + (t + j * 256) * 8);

    for (int kt = 0; kt < 8; ++kt) {
        __syncthreads();
        const int cur = kt & 1;
        bf16* Acur = sh + cur * 8192;
        bf16* Bcur = sh + 16384 + cur * 4096;
        if (kt < 7) {
            bf16* Anxt = sh + (1 - cur) * 8192;
            bf16* Bnxt = sh + 16384 + (1 - cur) * 4096;
            const int ko = (kt + 1) * 64;
            #pragma unroll
            for (int j = 0; j < 4; ++j)
                async16(aSrc + ko + (size_t)j * 32 * DIM, Anxt + (t + j * 256) * 8);
            #pragma unroll
            for (int j = 0; j < 2; ++j)
                async16(wSrc + ko + (size_t)j * 32 * DIM, Bnxt + (t + j * 256) * 8);
        }
        if (kt == ktr) {   // stash residual tile (uniform branch, once/block)
            #pragma unroll
            for (int j = 0; j < 4; ++j) {
                const int idx = t + j * 256;
                *(bf16x8*)(sh + 24576 + idx * 8) = *(const bf16x8*)(Acur + idx * 8);
            }
        }
        #pragma unroll
        for (int ks = 0; ks < 2; ++ks) {
            bf16x8 af[4], bfr[2];
            #pragma unroll
            for (int mi = 0; mi < 4; ++mi) {
                const int row = wr * 64 + mi * 16 + l16;
                af[mi] = *(const bf16x8*)(Acur + row * 64 + (((ks * 4 + quad) ^ (row & 7)) << 3));
            }
            #pragma unroll
            for (int ni = 0; ni < 2; ++ni) {
                const int row = wc * 32 + ni * 16 + l16;
                bfr[ni] = *(const bf16x8*)(Bcur + row * 64 + (((ks * 4 + quad) ^ (row & 7)) << 3));
            }
            #pragma unroll
            for (int mi = 0; mi < 4; ++mi)
                #pragma unroll
                for (int ni = 0; ni < 2; ++ni)
                    acc[mi][ni] = __builtin_amdgcn_mfma_f32_16x16x32_bf16(
                        af[mi], bfr[ni], acc[mi][ni], 0, 0, 0);
        }
    }
    __syncthreads();       // R complete (covers ktr == 7)

    for (int ni = 0; ni < 2; ++ni) {
        const int n = n0 + wc * 32 + ni * 16 + l16;
        const int cl = wc * 32 + ni * 16 + l16;          // local col in R
        const int chi = cl >> 3, clo = cl & 7;
        const float bb = bias[n];
        for (int mi = 0; mi < 4; ++mi) {
            for (int r = 0; r < 4; ++r) {
                const int rl = wr * 64 + mi * 16 + quad * 4 + r;   // local row
                const float ov = (float)sh[24576 + rl * 64 + ((chi ^ (rl & 7)) << 3) + clo];
                Yb[(size_t)(m0 + rl) * DIM + n] = (bf16)(ov + fmaxf(acc[mi][ni][r] + bb, 0.f));
            }
        }
    }
}

// ---------------------------------------------------------------------------
// ln: LayerNorm over last dim (512). One wave per row; bf16 in, fp32 out.
// ---------------------------------------------------------------------------
__global__ __launch_bounds__(256) void ln_kernel(
    const bf16* __restrict__ Y, const float* __restrict__ gamma,
    const float* __restrict__ beta, float* __restrict__ out)
{
    const int row  = blockIdx.x * 4 + (threadIdx.x >> 6);
    const int lane = threadIdx.x & 63;
    bf16x8 v = *(const bf16x8*)(Y + (size_t)row * DIM + lane * 8);
    float f[8];
    float s = 0.f, sq = 0.f;
    #pragma unroll
    for (int j = 0; j < 8; ++j) {
        f[j] = (float)v[j];
        s += f[j];
        sq += f[j] * f[j];
    }
    for (int mk = 32; mk >= 1; mk >>= 1) {
        s  += __shfl_xor(s,  mk, 64);
        sq += __shfl_xor(sq, mk, 64);
    }
    const float mu  = s * (1.f / 512.f);
    const float var = sq * (1.f / 512.f) - mu * mu;
    const float inv = rsqrtf(var + 1e-5f);
    float4 g1 = ((const float4*)gamma)[lane * 2];
    float4 g2 = ((const float4*)gamma)[lane * 2 + 1];
    float4 b1 = ((const float4*)beta)[lane * 2];
    float4 b2 = ((const float4*)beta)[lane * 2 + 1];
    float4 o1, o2;
    o1.x = (f[0] - mu) * inv * g1.x + b1.x;
    o1.y = (f[1] - mu) * inv * g1.y + b1.y;
    o1.z = (f[2] - mu) * inv * g1.z + b1.z;
    o1.w = (f[3] - mu) * inv * g1.w + b1.w;
    o2.x = (f[4] - mu) * inv * g2.x + b2.x;
    o2.y = (f[5] - mu) * inv * g2.y + b2.y;
    o2.z = (f[6] - mu) * inv * g2.z + b2.z;
    o2.w = (f[7] - mu) * inv * g2.w + b2.w;
    float* orow = out + (size_t)row * DIM;
    ((float4*)orow)[lane * 2]     = o1;
    ((float4*)orow)[lane * 2 + 1] = o2;
}

// ---------------------------------------------------------------------------
extern "C" void kernel_launch(void* const* d_in, const int* in_sizes, int n_in,
                              void* d_out, int out_size, void* d_ws, size_t ws_size,
                              hipStream_t stream) {
    const float* Q  = (const float*)d_in[0];
    const float* K  = (const float*)d_in[1];
    const int*   mask = (const int*)d_in[2];
    const float* Wq = (const float*)d_in[3];
    const float* bq = (const float*)d_in[4];
    const float* Wk = (const float*)d_in[5];
    const float* bk = (const float*)d_in[6];
    const float* Wv = (const float*)d_in[7];
    const float* bv = (const float*)d_in[8];
    const float* Wo = (const float*)d_in[9];
    const float* bo = (const float*)d_in[10];
    const float* gamma = (const float*)d_in[11];
    const float* beta  = (const float*)d_in[12];

    char* ws = (char*)d_ws;
    bf16* Wt  = (bf16*)(ws);                   // 2 MB (4 x 512x512 bf16, transposed)
    bf16* Qb  = (bf16*)(ws + 2097152);         // 8 MB
    bf16* Kb  = (bf16*)(ws + 10485760);        // 8 MB
    bf16* Qp  = (bf16*)(ws + 18874368);        // 8 MB  [b,h,q,64] (pre-scaled)
    bf16* Kp  = (bf16*)(ws + 27262976);        // 8 MB  [b,h,k,64]
    bf16* Vpt = (bf16*)(ws + 35651584);        // 8 MB  [b,h,d,1024]
    bf16* Oa  = (bf16*)(ws + 44040192);        // 8 MB  [b,q,512]
    bf16* Yb  = (bf16*)(ws + 52428800);        // 8 MB  [b,q,512] bf16
    float* out = (float*)d_out;

    prep_fused<<<4352, 256, 0, stream>>>(Q, K, Wq, Wk, Wv, Wo, Qb, Kb, Wt);
    proj_fused<<<1536, 256, 0, stream>>>(Qb, Kb, Wt, bq, bk, bv, Qp, Kp, Vpt);
    attn_kernel<<<1024, 256, 0, stream>>>(Qp, Kp, Vpt, mask, Oa);
    ffn_gemm<<<512, 256, 0, stream>>>(Oa, Wt + 3 * 262144, bo, Yb);
    ln_kernel<<<2048, 256, 0, stream>>>(Yb, gamma, beta, out);
}